// Round 9
// baseline (3218.984 us; speedup 1.0000x reference)
//
#include <hip/hip_runtime.h>
#include <math.h>

constexpr int B_ = 8;
constexpr int N_ = 2048;
constexpr int D_ = 128;
constexpr long long NDl = (long long)N_ * D_;     // 262144
constexpr long long NNl = (long long)N_ * N_;     // 4194304
constexpr float INV_TAU = 1.0f / 0.3f;
constexpr float SCALE_ = 20.0f;
constexpr float EPS_ = 1e-12f;

typedef __attribute__((ext_vector_type(8))) short short8;
typedef __attribute__((ext_vector_type(4))) float f32x4;
#define MFMA_BF16 __builtin_amdgcn_mfma_f32_16x16x32_bf16

// ---------------- workspace layout (float units) ----------------
constexpr size_t FL_F  = (size_t)B_ * NDl;   // 2097152
constexpr size_t FL_NN = (size_t)B_ * NNl;   // 33554432
constexpr size_t FL_V  = (size_t)B_ * N_;    // 16384

constexpr size_t OFF_SQ   = 0;
constexpr size_t OFF_ROWM = OFF_SQ   + FL_V;
constexpr size_t OFF_ROWZ = OFF_ROWM + FL_V;
constexpr size_t OFF_U0   = OFF_ROWZ + FL_V;
constexpr size_t OFF_V0   = OFF_U0   + FL_V;
constexpr size_t OFF_DIAG = OFF_V0   + FL_V;
constexpr size_t OFF_AV   = OFF_DIAG + FL_V;
constexpr size_t OFF_BV   = OFF_AV   + FL_V;
constexpr size_t OFF_ACC  = OFF_BV   + FL_V;      // 16 floats (incl. barrier ints at +8,+9)
constexpr size_t OFF_PM   = OFF_ACC  + 16;        // 32 chunks
constexpr size_t OFF_PS   = OFF_PM   + 32 * FL_V;
constexpr size_t OFF_PT   = OFF_PS   + 32 * FL_V; // 32 chunks
// aliases (time-disjoint): CP spans PM..PM+128*FL_V ; PCM/PCS inside PT
constexpr size_t OFF_CP   = OFF_PM;               // 128 stripes (init) / 32 stripes (persistent)
constexpr size_t OFF_PCM  = OFF_PT;
constexpr size_t OFF_PCS  = OFF_PT + 16 * FL_V;
constexpr size_t OFF_C    = OFF_PM + 128 * FL_V;
constexpr size_t OFF_K    = OFF_C  + FL_NN;       // bf16 K (FL_NN ushort)
constexpr size_t OFF_BF   = OFF_K  + FL_NN / 2;   // 8 bf16 arrays, each FL_F ushorts
// total ≈ 234 MB (proven to fit)

// ---------------- helpers ----------------
__device__ inline float bf2f(unsigned int lo16) {
  return __uint_as_float(lo16 << 16);
}
__device__ inline unsigned int f2bf(float x) {  // RNE bf16
  unsigned int u = __float_as_uint(x);
  u += 0x7fffu + ((u >> 16) & 1u);
  return (u >> 16) & 0xffffu;
}

// async global -> LDS, 16B per lane. lds dest = lbase + lane*16 (HW semantics).
__device__ inline void gload16(const unsigned short* g, unsigned short* lbase, int lane) {
#if defined(__has_builtin)
#if __has_builtin(__builtin_amdgcn_global_load_lds)
  __builtin_amdgcn_global_load_lds(
      (const __attribute__((address_space(1))) unsigned int*)g,
      (__attribute__((address_space(3))) unsigned int*)lbase, 16, 0, 0);
  return;
#endif
#endif
  *(uint4*)(lbase + lane * 8) = *(const uint4*)g;  // fallback
}

// device-scope grid barrier (manual, graph-capture-safe). All NB blocks must be
// co-resident: NB=256 blocks of 1024 thr / 64KB LDS -> >=2 blocks/CU capacity. OK.
__device__ inline void gbar(int* cnt, int* gen, int nblocks, int target) {
  __syncthreads();   // compiler emits vmcnt(0) drain: all block stores complete
  if (threadIdx.x == 0) {
    __threadfence(); // device-scope release of this block's writes
    int t = __hip_atomic_fetch_add(cnt, 1, __ATOMIC_ACQ_REL, __HIP_MEMORY_SCOPE_AGENT);
    if (t == nblocks - 1) {
      __hip_atomic_store(cnt, 0, __ATOMIC_RELAXED, __HIP_MEMORY_SCOPE_AGENT);
      __hip_atomic_fetch_add(gen, 1, __ATOMIC_ACQ_REL, __HIP_MEMORY_SCOPE_AGENT);
    } else {
      while (__hip_atomic_load(gen, __ATOMIC_ACQUIRE, __HIP_MEMORY_SCOPE_AGENT) < target) {
        __builtin_amdgcn_s_sleep(2);
      }
    }
    __threadfence(); // device-scope acquire (invalidate stale cache lines)
  }
  __syncthreads();
}

// ---------------- normalize: write split-bf16 f1/f2 ----------------
__global__ __launch_bounds__(64) void k_norm(const float* __restrict__ feats,
                                             unsigned short* __restrict__ f1hi,
                                             unsigned short* __restrict__ f1lo,
                                             unsigned short* __restrict__ f2hi,
                                             unsigned short* __restrict__ f2lo) {
  int r = blockIdx.x, b = blockIdx.y, which = blockIdx.z;
  const float* src = feats + ((size_t)(2 * b + which)) * NDl + (size_t)r * D_;
  int t = threadIdx.x;
  float2 x = *(const float2*)(src + 2 * t);
  float ss = x.x * x.x + x.y * x.y;
#pragma unroll
  for (int off = 32; off; off >>= 1) ss += __shfl_down(ss, off);
  ss = __shfl(ss, 0);
  float s = SCALE_ / fmaxf(sqrtf(ss), EPS_);
  float y0 = x.x * s, y1 = x.y * s;
  unsigned int h0 = f2bf(y0), h1 = f2bf(y1);
  unsigned int l0 = f2bf(y0 - bf2f(h0)), l1 = f2bf(y1 - bf2f(h1));
  size_t o = (size_t)b * NDl + (size_t)r * D_ + 2 * t;
  unsigned short* hb = (which ? f2hi : f1hi);
  unsigned short* lb = (which ? f2lo : f1lo);
  *(unsigned int*)(hb + o) = h0 | (h1 << 16);
  *(unsigned int*)(lb + o) = l0 | (l1 << 16);
}

// ---------------- transpose f1 -> f1t ([b][N][D] -> [b][D][N]) ----------------
__global__ __launch_bounds__(256) void k_transpose(const unsigned short* __restrict__ hi,
                                                   const unsigned short* __restrict__ lo,
                                                   unsigned short* __restrict__ thi,
                                                   unsigned short* __restrict__ tlo) {
  __shared__ unsigned short tile[64][66];
  int rt = blockIdx.x, dt = blockIdx.y, z = blockIdx.z;
  int b = z >> 1;
  const unsigned short* s = ((z & 1) ? lo : hi) + (size_t)b * NDl;
  unsigned short* d = ((z & 1) ? tlo : thi) + (size_t)b * NDl;
  int t = threadIdx.x;
  int r = t >> 2, c0 = (t & 3) * 16;
#pragma unroll
  for (int h = 0; h < 2; ++h) {
    uint4 v = *(const uint4*)(s + (size_t)(rt * 64 + r) * D_ + dt * 64 + c0 + h * 8);
    unsigned short* p = &tile[r][c0 + h * 8];
    p[0] = (unsigned short)v.x; p[1] = (unsigned short)(v.x >> 16);
    p[2] = (unsigned short)v.y; p[3] = (unsigned short)(v.y >> 16);
    p[4] = (unsigned short)v.z; p[5] = (unsigned short)(v.z >> 16);
    p[6] = (unsigned short)v.w; p[7] = (unsigned short)(v.w >> 16);
  }
  __syncthreads();
  int dd = t >> 2, r0 = (t & 3) * 16;
#pragma unroll
  for (int h = 0; h < 2; ++h) {
    unsigned int q[4];
#pragma unroll
    for (int e = 0; e < 4; ++e) {
      unsigned short a0 = tile[r0 + h * 8 + 2 * e][dd];
      unsigned short a1 = tile[r0 + h * 8 + 2 * e + 1][dd];
      q[e] = (unsigned int)a0 | ((unsigned int)a1 << 16);
    }
    uint4 v; v.x = q[0]; v.y = q[1]; v.z = q[2]; v.w = q[3];
    *(uint4*)(d + (size_t)(dt * 64 + dd) * N_ + rt * 64 + r0 + h * 8) = v;
  }
}

// ---------------- |x|^2 ----------------
__global__ __launch_bounds__(256) void k_sq(const float* __restrict__ pc0,
                                            float* __restrict__ sq) {
  int i = blockIdx.x * 256 + threadIdx.x;
  if (i < B_ * N_) {
    float x = pc0[3 * i], y = pc0[3 * i + 1], z = pc0[3 * i + 2];
    sq[i] = x * x + y * y + z * z;
  }
}

// ---------------- MFMA split-bf16: C = A @ B^T + fused row stats ----------------
template<bool WRITEC, bool TAU, bool SD, bool DIAG>
__global__ __launch_bounds__(256, 2) void k_mm(
    const unsigned short* __restrict__ Ahi_g, const unsigned short* __restrict__ Alo_g,
    const unsigned short* __restrict__ Bhi_g, const unsigned short* __restrict__ Blo_g,
    float* __restrict__ Cb, int roll,
    float* __restrict__ pms, float* __restrict__ pss, float* __restrict__ pts,
    float* __restrict__ diagb,
    const float* __restrict__ pc0, const float* __restrict__ sqv) {
  int bm = blockIdx.x, bn = blockIdx.y, z = blockIdx.z;
  int zb = (z + roll) & 7;
  const unsigned short* A_hi = Ahi_g + (size_t)z * NDl;
  const unsigned short* A_lo = Alo_g + (size_t)z * NDl;
  const unsigned short* B_hi = Bhi_g + (size_t)zb * NDl;
  const unsigned short* B_lo = Blo_g + (size_t)zb * NDl;
  float* C = Cb + (size_t)z * NNl;

  __shared__ __align__(16) unsigned short sAh[128 * 64], sAl[128 * 64];
  __shared__ __align__(16) unsigned short sBh[128 * 64], sBl[128 * 64];
  __shared__ float rpx[128], rpy[128], rpz[128], rps[128];
  __shared__ float cqx[128], cqy[128], cqz[128], cqs[128];

  int t = threadIdx.x;
  int lane = t & 63, w = t >> 6;
  int wm = w >> 1, wn = w & 1;

  if constexpr (SD) {
    const float* xb = pc0 + (size_t)z * N_ * 3;
    const float* sb = sqv + (size_t)z * N_;
    if (t < 128) {
      int r = bm * 128 + t;
      rpx[t] = xb[3 * r]; rpy[t] = xb[3 * r + 1]; rpz[t] = xb[3 * r + 2]; rps[t] = sb[r];
    } else {
      int c = bn * 128 + (t - 128);
      cqx[t - 128] = xb[3 * c]; cqy[t - 128] = xb[3 * c + 1]; cqz[t - 128] = xb[3 * c + 2];
      cqs[t - 128] = sb[c];
    }
  }

  f32x4 acc[4][4] = {};

  for (int kc = 0; kc < D_; kc += 64) {
    if (kc) __syncthreads();
#pragma unroll
    for (int i = 0; i < 4; ++i) {
      int li = i * 256 + t;
      int r = li >> 3;            // 0..127
      int j = li & 7;             // 16B block in row
      int xoff = (j * 8) ^ ((r & 7) << 3);   // swizzled source offset (ushorts)
      size_t grow_a = (size_t)(bm * 128 + r) * D_ + kc + xoff;
      size_t grow_b = (size_t)(bn * 128 + r) * D_ + kc + xoff;
      int wbase = (i * 256 + (t & 192)) * 8; // wave-uniform linear LDS base (ushorts)
      gload16(A_hi + grow_a, &sAh[wbase], lane);
      gload16(A_lo + grow_a, &sAl[wbase], lane);
      gload16(B_hi + grow_b, &sBh[wbase], lane);
      gload16(B_lo + grow_b, &sBl[wbase], lane);
    }
    __syncthreads();

    short8 ah[4][2], al[4][2];
#pragma unroll
    for (int m = 0; m < 4; ++m)
#pragma unroll
      for (int ks = 0; ks < 2; ++ks) {
        int row = wm * 64 + m * 16 + (lane & 15);
        int kb = ks * 64 + ((lane >> 4) * 16);
        int idx = (row * 128 + (kb ^ ((row & 7) << 4))) >> 1;
        ah[m][ks] = *(const short8*)(&sAh[idx]);
        al[m][ks] = *(const short8*)(&sAl[idx]);
      }
#pragma unroll
    for (int n = 0; n < 4; ++n) {
#pragma unroll
      for (int ks = 0; ks < 2; ++ks) {
        int row = wn * 64 + n * 16 + (lane & 15);
        int kb = ks * 64 + ((lane >> 4) * 16);
        int idx = (row * 128 + (kb ^ ((row & 7) << 4))) >> 1;
        short8 bh = *(const short8*)(&sBh[idx]);
        short8 bl = *(const short8*)(&sBl[idx]);
#pragma unroll
        for (int m = 0; m < 4; ++m) {
          acc[m][n] = MFMA_BF16(ah[m][ks], bh, acc[m][n], 0, 0, 0);
          acc[m][n] = MFMA_BF16(ah[m][ks], bl, acc[m][n], 0, 0, 0);
          acc[m][n] = MFMA_BF16(al[m][ks], bh, acc[m][n], 0, 0, 0);
        }
      }
    }
  }

  int lrow = (lane >> 4) * 4;
  int lcol = lane & 15;

  if constexpr (WRITEC) {
#pragma unroll
    for (int m = 0; m < 4; ++m) {
      int gr0 = bm * 128 + wm * 64 + m * 16 + lrow;
#pragma unroll
      for (int n = 0; n < 4; ++n) {
        int gc = bn * 128 + wn * 64 + n * 16 + lcol;
        float* Cp = C + (size_t)gr0 * N_ + gc;
#pragma unroll
        for (int rg = 0; rg < 4; ++rg)
          Cp[(size_t)rg * N_] = acc[m][n][rg];
      }
    }
  }

  // per-row stats over this wave's 64 cols -> chunk (bn*2+wn)
#pragma unroll
  for (int m = 0; m < 4; ++m) {
#pragma unroll
    for (int rg = 0; rg < 4; ++rg) {
      int rib = wm * 64 + m * 16 + lrow + rg;
      float v0 = acc[m][0][rg], v1 = acc[m][1][rg], v2 = acc[m][2][rg], v3 = acc[m][3][rg];
      float mx = fmaxf(fmaxf(v0, v1), fmaxf(v2, v3));
#pragma unroll
      for (int msk = 1; msk < 16; msk <<= 1) mx = fmaxf(mx, __shfl_xor(mx, msk));
      float e0 = __expf(v0 - mx), e1 = __expf(v1 - mx), e2 = __expf(v2 - mx), e3 = __expf(v3 - mx);
      float s = e0 + e1 + e2 + e3;
      float st = 0.f, sd = 0.f;
      if constexpr (TAU)
        st = __expf((v0 - mx) * INV_TAU) + __expf((v1 - mx) * INV_TAU) +
             __expf((v2 - mx) * INV_TAU) + __expf((v3 - mx) * INV_TAU);
      if constexpr (SD) {
        float xi = rpx[rib], yi = rpy[rib], zi = rpz[rib], si = rps[rib];
#pragma unroll
        for (int n = 0; n < 4; ++n) {
          int ci = wn * 64 + n * 16 + lcol;
          float d2 = fmaxf(si + cqs[ci] - 2.f * (xi * cqx[ci] + yi * cqy[ci] + zi * cqz[ci]), 0.f);
          float en = (n == 0) ? e0 : (n == 1) ? e1 : (n == 2) ? e2 : e3;
          sd += en * sqrtf(sqrtf(d2));
        }
      }
#pragma unroll
      for (int msk = 1; msk < 16; msk <<= 1) {
        s += __shfl_xor(s, msk);
        if constexpr (TAU) st += __shfl_xor(st, msk);
        if constexpr (SD) sd += __shfl_xor(sd, msk);
      }
      if (lcol == 0) {
        size_t idx = ((size_t)(z * 32 + bn * 2 + wn)) * N_ + bm * 128 + rib;
        pms[idx] = mx; pss[idx] = s;
        if constexpr (TAU) pts[idx] = st;
        if constexpr (SD) pts[idx] = sd;
      }
    }
  }

  if constexpr (DIAG) {
    if (bm == bn && wm == wn) {
#pragma unroll
      for (int m = 0; m < 4; ++m)
#pragma unroll
        for (int rg = 0; rg < 4; ++rg) {
          int rr = lrow + rg;
          if (lcol == rr)
            diagb[(size_t)z * N_ + bm * 128 + wm * 64 + m * 16 + rr] = acc[m][m][rg];
        }
    }
  }
}

// ---------------- combine tile stats -> rowm/rowZ/u0 + scalar accumulations ----------------
template<bool WMZ, bool TAU, bool SD, bool DIAG, bool MATCH>
__global__ __launch_bounds__(256) void k_comb(const float* __restrict__ pms,
                                              const float* __restrict__ pss,
                                              const float* __restrict__ pts,
                                              const float* __restrict__ diagb,
                                              float* __restrict__ rowm,
                                              float* __restrict__ rowZ,
                                              float* __restrict__ u0,
                                              float* __restrict__ acc) {
  int b = blockIdx.y;
  int r = blockIdx.x * 256 + threadIdx.x;
  float M = -INFINITY, S = 0.f, ST = 0.f, SDa = 0.f;
#pragma unroll
  for (int p = 0; p < 32; ++p) {
    size_t idx = ((size_t)(b * 32 + p)) * N_ + r;
    float m = pms[idx], s = pss[idx];
    float M2 = fmaxf(M, m);
    float f0 = __expf(M - M2), f1 = __expf(m - M2);
    S = S * f0 + s * f1;
    if constexpr (TAU) ST = ST * __expf((M - M2) * INV_TAU) + pts[idx] * __expf((m - M2) * INV_TAU);
    if constexpr (SD)  SDa = SDa * f0 + pts[idx] * f1;
    M = M2;
  }
  size_t vr = (size_t)b * N_ + r;
  if constexpr (WMZ) { rowm[vr] = M; rowZ[vr] = S; }
  if constexpr (TAU) u0[vr] = M * INV_TAU + __logf(ST);
  float contrib = 0.f; int slot = -1;
  if constexpr (SD)    { contrib = SDa / S; slot = 0; }
  if constexpr (DIAG)  { contrib = __expf(diagb[vr] - M) / S; slot = 3; }
  if constexpr (MATCH) { contrib = (diagb[vr] == M) ? 1.f : 0.f; slot = 4; }
  if (slot >= 0) {
    __shared__ float red[256];
    int t = threadIdx.x;
    red[t] = contrib; __syncthreads();
    for (int off = 128; off; off >>= 1) { if (t < off) red[t] += red[t + off]; __syncthreads(); }
    if (t == 0) atomicAdd(acc + slot, red[0]);
  }
}

// ---------------- MFMA: Out = softmax(C) @ W (BM=64, 256 blocks, 3/CU) ----------------
__global__ __launch_bounds__(256, 3) void k_smmm(
    const float* __restrict__ Cb, const float* __restrict__ rowm, const float* __restrict__ rowZ,
    const unsigned short* __restrict__ Wthi, const unsigned short* __restrict__ Wtlo,
    unsigned short* __restrict__ Ohi, unsigned short* __restrict__ Olo, int roll) {
  int bm = blockIdx.x, z = blockIdx.y;   // bm in 0..31
  int zb = (z + roll) & 7;
  const float* C = Cb + (size_t)z * NNl + (size_t)(bm * 64) * N_;
  const unsigned short* Wh = Wthi + (size_t)zb * NDl;
  const unsigned short* Wl = Wtlo + (size_t)zb * NDl;

  __shared__ __align__(16) unsigned short sPh[64 * 64], sPl[64 * 64];
  __shared__ __align__(16) unsigned short sWh[128 * 64], sWl[128 * 64];
  __shared__ float s_rm[64], s_rz[64];

  int t = threadIdx.x, lane = t & 63, w = t >> 6;
  if (t < 64) {
    s_rm[t] = rowm[(size_t)z * N_ + bm * 64 + t];
    s_rz[t] = rowZ[(size_t)z * N_ + bm * 64 + t];
  }
  __syncthreads();

  f32x4 acc[8] = {};

  for (int jc = 0; jc < N_; jc += 64) {
    if (jc) __syncthreads();
    // P staging (compute exp + split), 64 rows x 64 j
#pragma unroll
    for (int i = 0; i < 4; ++i) {
      int li = i * 256 + t;
      int r = li >> 4;
      int j4 = (li & 15) * 4;
      float4 c4 = *(const float4*)(C + (size_t)r * N_ + jc + j4);
      float rm = s_rm[r];
      float p0 = __expf(c4.x - rm), p1 = __expf(c4.y - rm);
      float p2 = __expf(c4.z - rm), p3 = __expf(c4.w - rm);
      unsigned int h0 = f2bf(p0), h1 = f2bf(p1), h2 = f2bf(p2), h3 = f2bf(p3);
      unsigned int l0 = f2bf(p0 - bf2f(h0)), l1 = f2bf(p1 - bf2f(h1));
      unsigned int l2 = f2bf(p2 - bf2f(h2)), l3 = f2bf(p3 - bf2f(h3));
      int kb = j4 * 2;
      int sidx = (r * 128 + (kb ^ ((r & 7) << 4))) >> 1;
      uint2 ph; ph.x = h0 | (h1 << 16); ph.y = h2 | (h3 << 16);
      uint2 pl; pl.x = l0 | (l1 << 16); pl.y = l2 | (l3 << 16);
      *(uint2*)(&sPh[sidx]) = ph;
      *(uint2*)(&sPl[sidx]) = pl;
    }
    // W staging (pre-transposed bf16) via global_load_lds, linear dest + swizzled src
#pragma unroll
    for (int i = 0; i < 4; ++i) {
      int li = i * 256 + t;
      int d = li >> 3;
      int j = li & 7;
      int xoff = (j * 8) ^ ((d & 7) << 3);
      size_t ga = (size_t)d * N_ + jc + xoff;
      int wbase = (i * 256 + (t & 192)) * 8;
      gload16(Wh + ga, &sWh[wbase], lane);
      gload16(Wl + ga, &sWl[wbase], lane);
    }
    __syncthreads();

    short8 ph[2], pl[2];
#pragma unroll
    for (int ks = 0; ks < 2; ++ks) {
      int row = w * 16 + (lane & 15);
      int kb = ks * 64 + ((lane >> 4) * 16);
      int idx = (row * 128 + (kb ^ ((row & 7) << 4))) >> 1;
      ph[ks] = *(const short8*)(&sPh[idx]);
      pl[ks] = *(const short8*)(&sPl[idx]);
    }
#pragma unroll
    for (int n = 0; n < 8; ++n) {
#pragma unroll
      for (int ks = 0; ks < 2; ++ks) {
        int row = n * 16 + (lane & 15);
        int kb = ks * 64 + ((lane >> 4) * 16);
        int idx = (row * 128 + (kb ^ ((row & 7) << 4))) >> 1;
        short8 bh = *(const short8*)(&sWh[idx]);
        short8 bl = *(const short8*)(&sWl[idx]);
        acc[n] = MFMA_BF16(ph[ks], bh, acc[n], 0, 0, 0);
        acc[n] = MFMA_BF16(ph[ks], bl, acc[n], 0, 0, 0);
        acc[n] = MFMA_BF16(pl[ks], bh, acc[n], 0, 0, 0);
      }
    }
  }

  // epilogue: /Z, split bf16, store
  unsigned short* OhB = Ohi + (size_t)z * NDl;
  unsigned short* OlB = Olo + (size_t)z * NDl;
#pragma unroll
  for (int rg = 0; rg < 4; ++rg) {
    int rib = w * 16 + (lane >> 4) * 4 + rg;
    float iZ = 1.f / s_rz[rib];
    size_t ro = (size_t)(bm * 64 + rib) * D_;
#pragma unroll
    for (int n = 0; n < 8; ++n) {
      int d = n * 16 + (lane & 15);
      float vv = acc[n][rg] * iZ;
      unsigned int h = f2bf(vv);
      OhB[ro + d] = (unsigned short)h;
      OlB[ro + d] = (unsigned short)f2bf(vv - bf2f(h));
    }
  }
}

// ---------------- col LSE of (C/tau - u0) -> partials ----------------
__global__ __launch_bounds__(256) void k_colLSE(const float* __restrict__ Cb,
                                                const float* __restrict__ u0,
                                                float* __restrict__ pcm,
                                                float* __restrict__ pcs) {
  int jb = blockIdx.x, ch = blockIdx.y, b = blockIdx.z;
  int t = threadIdx.x;
  int j4 = (jb * 256 + t) * 4;
  __shared__ float su[128];
  if (t < 128) su[t] = u0[(size_t)b * N_ + ch * 128 + t];
  __syncthreads();
  const float* Cp = Cb + (size_t)b * NNl + (size_t)(ch * 128) * N_ + j4;
  float m0 = -INFINITY, m1 = -INFINITY, m2 = -INFINITY, m3 = -INFINITY;
  float s0 = 0.f, s1 = 0.f, s2 = 0.f, s3 = 0.f;
#pragma unroll 4
  for (int i = 0; i < 128; ++i) {
    float4 c = *(const float4*)(Cp + (size_t)i * N_);
    float ui = su[i];
    float x0 = c.x * INV_TAU - ui, x1 = c.y * INV_TAU - ui;
    float x2 = c.z * INV_TAU - ui, x3 = c.w * INV_TAU - ui;
    float M0 = fmaxf(m0, x0); s0 = s0 * __expf(m0 - M0) + __expf(x0 - M0); m0 = M0;
    float M1 = fmaxf(m1, x1); s1 = s1 * __expf(m1 - M1) + __expf(x1 - M1); m1 = M1;
    float M2 = fmaxf(m2, x2); s2 = s2 * __expf(m2 - M2) + __expf(x2 - M2); m2 = M2;
    float M3 = fmaxf(m3, x3); s3 = s3 * __expf(m3 - M3) + __expf(x3 - M3); m3 = M3;
  }
  size_t o = ((size_t)(b * 16 + ch)) * N_ + j4;
  float4 vm; vm.x = m0; vm.y = m1; vm.z = m2; vm.w = m3;
  float4 vs; vs.x = s0; vs.y = s1; vs.z = s2; vs.w = s3;
  *(float4*)(pcm + o) = vm;
  *(float4*)(pcs + o) = vs;
}

__global__ __launch_bounds__(256) void k_colLSEcomb(const float* __restrict__ pcm,
                                                    const float* __restrict__ pcs,
                                                    float* __restrict__ v0) {
  int b = blockIdx.y; int j = blockIdx.x * 256 + threadIdx.x;
  float m = -INFINITY, s = 0.f;
#pragma unroll
  for (int ch = 0; ch < 16; ++ch) {
    size_t idx = ((size_t)(b * 16 + ch)) * N_ + j;
    float m2 = pcm[idx], s2 = pcs[idx];
    float M = fmaxf(m, m2);
    s = s * __expf(m - M) + s2 * __expf(m2 - M);
    m = M;
  }
  v0[(size_t)b * N_ + j] = m + __logf(s);
}

// ---------------- sinkhorn init: read C, write K, first linear iter ----------------
__global__ __launch_bounds__(256) void k_sink_init(const float* __restrict__ Cb,
                                                   unsigned short* __restrict__ Kp,
                                                   const float* __restrict__ u0,
                                                   const float* __restrict__ v0,
                                                   float* __restrict__ avec,
                                                   float* __restrict__ cp) {
  int stripe = blockIdx.x, b = blockIdx.y;   // stripe 0..127
  int i0 = stripe * 16;
  int t = threadIdx.x;
  int w = t >> 6, l = t & 63;
  __shared__ float a_s[16];
  float bv[4][8];
  const float* vsrc = v0 + (size_t)b * N_;
#pragma unroll
  for (int c = 0; c < 4; ++c) {
    float4 q0 = *(const float4*)(vsrc + c * 512 + l * 8);
    float4 q1 = *(const float4*)(vsrc + c * 512 + l * 8 + 4);
    bv[c][0] = q0.x; bv[c][1] = q0.y; bv[c][2] = q0.z; bv[c][3] = q0.w;
    bv[c][4] = q1.x; bv[c][5] = q1.y; bv[c][6] = q1.z; bv[c][7] = q1.w;
  }
  unsigned short* Kb = Kp + (size_t)b * NNl;
  const float* Cbb = Cb + (size_t)b * NNl;
#pragma unroll
  for (int ii = 0; ii < 4; ++ii) {
    int i = w * 4 + ii;
    int row = i0 + i;
    float r = 0.f;
    float ub = u0[(size_t)b * N_ + row];
    const float* Crow = Cbb + (size_t)row * N_;
    unsigned short* Krow = Kb + (size_t)row * N_;
#pragma unroll
    for (int c = 0; c < 4; ++c) {
      float4 c0 = *(const float4*)(Crow + c * 512 + l * 8);
      float4 c1 = *(const float4*)(Crow + c * 512 + l * 8 + 4);
      float cv[8] = {c0.x, c0.y, c0.z, c0.w, c1.x, c1.y, c1.z, c1.w};
      float kv[8];
#pragma unroll
      for (int e = 0; e < 8; ++e) { kv[e] = __expf(cv[e] * INV_TAU - ub - bv[c][e]); r += kv[e]; }
      uint4 pk;
      pk.x = f2bf(kv[0]) | (f2bf(kv[1]) << 16);
      pk.y = f2bf(kv[2]) | (f2bf(kv[3]) << 16);
      pk.z = f2bf(kv[4]) | (f2bf(kv[5]) << 16);
      pk.w = f2bf(kv[6]) | (f2bf(kv[7]) << 16);
      *(uint4*)(Krow + c * 512 + l * 8) = pk;
    }
#pragma unroll
    for (int off = 1; off < 64; off <<= 1) r += __shfl_xor(r, off);
    if (l == 0) {
      float a = 1.f / r;
      a_s[i] = a;
      avec[(size_t)b * N_ + row] = a;
    }
  }
  __threadfence_block();
  __syncthreads();
  float cpa[8] = {};
  const unsigned short* Kc = Kb + (size_t)i0 * N_ + w * 512 + l * 8;
#pragma unroll 4
  for (int i = 0; i < 16; ++i) {
    uint4 pk = *(const uint4*)(Kc + (size_t)i * N_);
    float ai = a_s[i];
    cpa[0] += bf2f(pk.x & 0xffffu) * ai; cpa[1] += bf2f(pk.x >> 16) * ai;
    cpa[2] += bf2f(pk.y & 0xffffu) * ai; cpa[3] += bf2f(pk.y >> 16) * ai;
    cpa[4] += bf2f(pk.z & 0xffffu) * ai; cpa[5] += bf2f(pk.z >> 16) * ai;
    cpa[6] += bf2f(pk.w & 0xffffu) * ai; cpa[7] += bf2f(pk.w >> 16) * ai;
  }
  size_t o = ((size_t)(b * 128 + stripe)) * N_ + w * 512 + l * 8;
  float4 o0; o0.x = cpa[0]; o0.y = cpa[1]; o0.z = cpa[2]; o0.w = cpa[3];
  float4 o1; o1.x = cpa[4]; o1.y = cpa[5]; o1.z = cpa[6]; o1.w = cpa[7];
  *(float4*)(cp + o) = o0;
  *(float4*)(cp + o + 4) = o1;
}

__global__ __launch_bounds__(256) void k_bcomb(const float* __restrict__ cp,
                                               float* __restrict__ bvec) {
  int b = blockIdx.y; int j = blockIdx.x * 256 + threadIdx.x;
  float s0 = 0.f, s1 = 0.f, s2 = 0.f, s3 = 0.f;
#pragma unroll 8
  for (int st = 0; st < 128; st += 4) {
    s0 += cp[((size_t)(b * 128 + st + 0)) * N_ + j];
    s1 += cp[((size_t)(b * 128 + st + 1)) * N_ + j];
    s2 += cp[((size_t)(b * 128 + st + 2)) * N_ + j];
    s3 += cp[((size_t)(b * 128 + st + 3)) * N_ + j];
  }
  bvec[(size_t)b * N_ + j] = 1.f / ((s0 + s1) + (s2 + s3));
}

// ---------------- persistent sinkhorn: 28 linear iterations, manual grid barrier ----
// 256 blocks x 1024 threads, block = (b, 64-row stripe). Per iteration:
// 4x{stage 16-row chunk to LDS; phase1 row-dots (1 row/wave); phase2 col accumulate}
// -> write cp[b][rc][j] -> gbar -> 64-thread reduce -> bvec -> gbar.
__global__ __launch_bounds__(1024, 1) void k_sink_pers(
    const unsigned short* __restrict__ Kp,
    float* __restrict__ bvec,
    float* __restrict__ avec,
    float* __restrict__ cp, int iters,
    int* bar_cnt, int* bar_gen) {
  int blk = blockIdx.x;
  int b = blk >> 5, rc = blk & 31;
  int t = threadIdx.x;
  int w = t >> 6, l = t & 63;
  __shared__ __align__(16) unsigned short sK[16 * 2048];  // 64 KB chunk
  __shared__ float a_s[16];
  const unsigned short* Kb = Kp + (size_t)b * NNl + (size_t)(rc * 64) * N_;
  int barnum = 0;

  for (int it = 0; it < iters; ++it) {
    // bvec fragment for this lane's dot pattern
    float bv[4][8];
    const float* vsrc = bvec + (size_t)b * N_;
#pragma unroll
    for (int c = 0; c < 4; ++c) {
      float4 q0 = *(const float4*)(vsrc + c * 512 + l * 8);
      float4 q1 = *(const float4*)(vsrc + c * 512 + l * 8 + 4);
      bv[c][0] = q0.x; bv[c][1] = q0.y; bv[c][2] = q0.z; bv[c][3] = q0.w;
      bv[c][4] = q1.x; bv[c][5] = q1.y; bv[c][6] = q1.z; bv[c][7] = q1.w;
    }
    float cpa0 = 0.f, cpa1 = 0.f;
    for (int ch = 0; ch < 4; ++ch) {
      __syncthreads();   // previous chunk's phase2 done before overwriting sK / a_s
      // stage rows ch*16 .. ch*16+15 (64 KB), linear dest = linear src
#pragma unroll
      for (int i = 0; i < 4; ++i) {
        int li = i * 1024 + t;              // 4096 16B-chunks
        int wbase = (li & ~63) * 8;         // wave-uniform LDS base (ushorts)
        gload16(Kb + (size_t)(ch * 16) * N_ + (size_t)li * 8, &sK[wbase], l);
      }
      __syncthreads();   // drains global_load_lds
      // phase 1: wave w dots row w
      float r = 0.f;
#pragma unroll
      for (int c = 0; c < 4; ++c) {
        uint4 pk = *(const uint4*)(&sK[w * 2048 + c * 512 + l * 8]);
        r += bf2f(pk.x & 0xffffu) * bv[c][0] + bf2f(pk.x >> 16) * bv[c][1]
           + bf2f(pk.y & 0xffffu) * bv[c][2] + bf2f(pk.y >> 16) * bv[c][3]
           + bf2f(pk.z & 0xffffu) * bv[c][4] + bf2f(pk.z >> 16) * bv[c][5]
           + bf2f(pk.w & 0xffffu) * bv[c][6] + bf2f(pk.w >> 16) * bv[c][7];
      }
#pragma unroll
      for (int off = 1; off < 64; off <<= 1) r += __shfl_xor(r, off);
      if (l == 0) {
        float a = 1.f / r;
        a_s[w] = a;
        avec[(size_t)b * N_ + rc * 64 + ch * 16 + w] = a;
      }
      __syncthreads();
      // phase 2: thread t owns cols j=2t, 2t+1 over the 16 chunk rows
#pragma unroll
      for (int i = 0; i < 16; ++i) {
        unsigned int u = *(const unsigned int*)(&sK[i * 2048 + 2 * t]);
        float ai = a_s[i];
        cpa0 += bf2f(u & 0xffffu) * ai;
        cpa1 += bf2f(u >> 16) * ai;
      }
    }
    float2 o2; o2.x = cpa0; o2.y = cpa1;
    *(float2*)(cp + ((size_t)(b * 32 + rc)) * N_ + 2 * t) = o2;
    gbar(bar_cnt, bar_gen, 256, ++barnum);
    // reduce: this block computes bvec for b2 = blk>>5, j in [(blk&31)*64, +64)
    if (t < 64) {
      int b2 = blk >> 5;
      int j = (blk & 31) * 64 + t;
      float s = 0.f;
#pragma unroll
      for (int st = 0; st < 32; ++st)
        s += cp[((size_t)(b2 * 32 + st)) * N_ + j];
      bvec[(size_t)b2 * N_ + j] = 1.f / s;
    }
    gbar(bar_cnt, bar_gen, 256, ++barnum);
  }
}

// ---------------- final fused elementwise ----------------
__global__ __launch_bounds__(256) void k_felem(const float* __restrict__ Cb,
                                               const unsigned short* __restrict__ Kp,
                                               const float* __restrict__ rowm,
                                               const float* __restrict__ rowZ,
                                               const float* __restrict__ avec,
                                               const float* __restrict__ bvec,
                                               const float* __restrict__ pc0,
                                               const float* __restrict__ sqv,
                                               float* __restrict__ acc) {
  int rb = blockIdx.x, b = blockIdx.y;
  int i0 = rb * 16;
  int t = threadIdx.x;
  const float* xb = pc0 + (size_t)b * N_ * 3;
  const float* sqb = sqv + (size_t)b * N_;
  float xj[2][4], yj[2][4], zj[2][4], sj[2][4], bj[2][4];
#pragma unroll
  for (int kk = 0; kk < 2; ++kk) {
    int j4 = t * 4 + kk * 1024;
    float4 p0 = *(const float4*)(xb + 3 * j4);
    float4 p1 = *(const float4*)(xb + 3 * j4 + 4);
    float4 p2 = *(const float4*)(xb + 3 * j4 + 8);
    xj[kk][0] = p0.x; yj[kk][0] = p0.y; zj[kk][0] = p0.z;
    xj[kk][1] = p0.w; yj[kk][1] = p1.x; zj[kk][1] = p1.y;
    xj[kk][2] = p1.z; yj[kk][2] = p1.w; zj[kk][2] = p2.x;
    xj[kk][3] = p2.y; yj[kk][3] = p2.z; zj[kk][3] = p2.w;
    float4 s4 = *(const float4*)(sqb + j4);
    sj[kk][0] = s4.x; sj[kk][1] = s4.y; sj[kk][2] = s4.z; sj[kk][3] = s4.w;
    float4 b4 = *(const float4*)(bvec + (size_t)b * N_ + j4);
    bj[kk][0] = b4.x; bj[kk][1] = b4.y; bj[kk][2] = b4.z; bj[kk][3] = b4.w;
  }
  float aL = 0.f, aLc = 0.f, aP = 0.f;
  for (int ii = 0; ii < 16; ++ii) {
    int i = i0 + ii;
    float xi = xb[3 * i], yi = xb[3 * i + 1], zi = xb[3 * i + 2];
    float sqi = sqb[i];
    float mi = rowm[(size_t)b * N_ + i];
    float iZ = 1.f / rowZ[(size_t)b * N_ + i];
    float ai = avec[(size_t)b * N_ + i];
    const float* Crow = Cb + (size_t)b * NNl + (size_t)i * N_;
    const unsigned short* Krow = Kp + (size_t)b * NNl + (size_t)i * N_;
#pragma unroll
    for (int kk = 0; kk < 2; ++kk) {
      int j4 = t * 4 + kk * 1024;
      float4 c4 = *(const float4*)(Crow + j4);
      uint2 k2 = *(const uint2*)(Krow + j4);
      float kf[4] = { bf2f(k2.x & 0xffffu), bf2f(k2.x >> 16),
                      bf2f(k2.y & 0xffffu), bf2f(k2.y >> 16) };
      float cf[4] = { c4.x, c4.y, c4.z, c4.w };
#pragma unroll
      for (int e = 0; e < 4; ++e) {
        int j = j4 + e;
        float sm = __expf(cf[e] - mi) * iZ;
        float sink = kf[e] * ai * bj[kk][e];
        float d2 = fmaxf(sqi + sj[kk][e] - 2.f * (xi * xj[kk][e] + yi * yj[kk][e] + zi * zj[kk][e]), 0.f);
        aL += sqrtf(sqrtf(d2)) * sm;
        aLc += fabsf(sink - sm);
        aP += fabsf(((i == j) ? 1.f : 0.f) - sink);
      }
    }
  }
  __shared__ float red[256];
  red[t] = aL; __syncthreads();
  for (int off = 128; off; off >>= 1) { if (t < off) red[t] += red[t + off]; __syncthreads(); }
  if (t == 0) atomicAdd(acc + 0, red[0]);
  __syncthreads();
  red[t] = aLc; __syncthreads();
  for (int off = 128; off; off >>= 1) { if (t < off) red[t] += red[t + off]; __syncthreads(); }
  if (t == 0) atomicAdd(acc + 1, red[0]);
  __syncthreads();
  red[t] = aP; __syncthreads();
  for (int off = 128; off; off >>= 1) { if (t < off) red[t] += red[t + off]; __syncthreads(); }
  if (t == 0) atomicAdd(acc + 2, red[0]);
}

// ---------------- finalize ----------------
__global__ void k_finalize(const float* __restrict__ acc, float* __restrict__ out) {
  float invN = 1.0f / (float)N_;
  float L  = acc[0] * invN;
  float Lc = 3.f * acc[1] * invN;
  float P  = 3.f * acc[2] * invN;
  float Dg = -acc[3] * invN;
  float M  = acc[4];
  float invB = 1.0f / (float)B_;
  out[0] = (L + Lc) * invB;
  out[1] = L * invB;
  out[2] = Lc * invB;
  out[3] = P * invB;
  out[4] = M * invB;
  out[5] = Dg * invB;
}

extern "C" void kernel_launch(void* const* d_in, const int* in_sizes, int n_in,
                              void* d_out, int out_size, void* d_ws, size_t ws_size,
                              hipStream_t stream) {
  const float* feats = (const float*)d_in[0];
  const float* pc0 = (const float*)d_in[1];
  float* out = (float*)d_out;
  float* ws = (float*)d_ws;

  float* sqv   = ws + OFF_SQ;
  float* rowm  = ws + OFF_ROWM;
  float* rowZ  = ws + OFF_ROWZ;
  float* u0    = ws + OFF_U0;
  float* v0    = ws + OFF_V0;
  float* diagb = ws + OFF_DIAG;
  float* avec  = ws + OFF_AV;
  float* bvec  = ws + OFF_BV;
  float* acc   = ws + OFF_ACC;
  float* pms   = ws + OFF_PM;
  float* pss   = ws + OFF_PS;
  float* pts   = ws + OFF_PT;
  float* pcm   = ws + OFF_PCM;
  float* pcs   = ws + OFF_PCS;
  float* cp    = ws + OFF_CP;
  float* C     = ws + OFF_C;
  unsigned short* Kp = (unsigned short*)(ws + OFF_K);
  unsigned short* bfb = (unsigned short*)(ws + OFF_BF);
  unsigned short* f1hi   = bfb + 0 * FL_F;
  unsigned short* f1lo   = bfb + 1 * FL_F;
  unsigned short* f2hi   = bfb + 2 * FL_F;
  unsigned short* f2lo   = bfb + 3 * FL_F;
  unsigned short* f1t_hi = bfb + 4 * FL_F;
  unsigned short* f1t_lo = bfb + 5 * FL_F;
  unsigned short* fvahi  = bfb + 6 * FL_F;
  unsigned short* fvalo  = bfb + 7 * FL_F;
  int* bar_cnt = (int*)(acc + 8);
  int* bar_gen = (int*)(acc + 9);

  // zeroes scalar accumulators AND barrier state (graph replay re-runs this)
  hipMemsetAsync(acc, 0, 16 * sizeof(float), stream);

  k_norm<<<dim3(N_, B_, 2), 64, 0, stream>>>(feats, f1hi, f1lo, f2hi, f2lo);
  k_transpose<<<dim3(32, 2, 16), 256, 0, stream>>>(f1hi, f1lo, f1t_hi, f1t_lo);
  k_sq<<<(B_ * N_) / 256, 256, 0, stream>>>(pc0, sqv);

  dim3 mmGrid(N_ / 128, N_ / 128, B_);
  dim3 cbGrid(N_ / 256, B_);
  dim3 smGrid(N_ / 64, B_);

  // g-branch: fv = softmax(f1 f1^T) @ f1 ; d = -sum diag softmax(fv f1^T)
  k_mm<true, false, false, false><<<mmGrid, 256, 0, stream>>>(f1hi, f1lo, f1hi, f1lo, C, 0, pms, pss, pts, diagb, pc0, sqv);
  k_comb<true, false, false, false, false><<<cbGrid, 256, 0, stream>>>(pms, pss, pts, diagb, rowm, rowZ, u0, acc);
  k_smmm<<<smGrid, 256, 0, stream>>>(C, rowm, rowZ, f1t_hi, f1t_lo, fvahi, fvalo, 0);
  k_mm<false, false, false, true><<<mmGrid, 256, 0, stream>>>(fvahi, fvalo, f1hi, f1lo, C, 0, pms, pss, pts, diagb, pc0, sqv);
  k_comb<false, false, false, true, false><<<cbGrid, 256, 0, stream>>>(pms, pss, pts, diagb, rowm, rowZ, u0, acc);

  // corr_12 = f1 @ f2^T : loss term 2 (dist-weighted partials, no C write)
  k_mm<false, false, true, false><<<mmGrid, 256, 0, stream>>>(f1hi, f1lo, f2hi, f2lo, C, 0, pms, pss, pts, diagb, pc0, sqv);
  k_comb<false, false, true, false, false><<<cbGrid, 256, 0, stream>>>(pms, pss, pts, diagb, rowm, rowZ, u0, acc);

  // corr_1a = f1 @ fa^T ; f1_via_fa_t = softmax @ fa
  k_mm<true, false, false, false><<<mmGrid, 256, 0, stream>>>(f1hi, f1lo, f1hi, f1lo, C, 1, pms, pss, pts, diagb, pc0, sqv);
  k_comb<true, false, false, false, false><<<cbGrid, 256, 0, stream>>>(pms, pss, pts, diagb, rowm, rowZ, u0, acc);
  k_smmm<<<smGrid, 256, 0, stream>>>(C, rowm, rowZ, f1t_hi, f1t_lo, fvahi, fvalo, 1);

  // corr_1a2 = f1_via_fa_t @ f2^T : stats + tau-LSE + diag(match)
  k_mm<true, true, false, true><<<mmGrid, 256, 0, stream>>>(fvahi, fvalo, f2hi, f2lo, C, 0, pms, pss, pts, diagb, pc0, sqv);
  k_comb<true, true, false, false, true><<<cbGrid, 256, 0, stream>>>(pms, pss, pts, diagb, rowm, rowZ, u0, acc);

  // sinkhorn: log-domain first iteration (u0, v0), init K + first linear pair,
  // then 28 linear iterations in ONE persistent kernel with manual grid barrier
  k_colLSE<<<dim3(2, 16, B_), 256, 0, stream>>>(C, u0, pcm, pcs);
  k_colLSEcomb<<<cbGrid, 256, 0, stream>>>(pcm, pcs, v0);
  k_sink_init<<<dim3(128, B_), 256, 0, stream>>>(C, Kp, u0, v0, avec, cp);
  k_bcomb<<<cbGrid, 256, 0, stream>>>(cp, bvec);
  k_sink_pers<<<dim3(256), dim3(1024), 0, stream>>>(Kp, bvec, avec, cp, 28, bar_cnt, bar_gen);

  // final fused elementwise
  k_felem<<<dim3(N_ / 16, B_), 256, 0, stream>>>(C, Kp, rowm, rowZ, avec, bvec, pc0, sqv, acc);

  k_finalize<<<1, 1, 0, stream>>>(acc, out);
}

// Round 10
// 1425.500 us; speedup vs baseline: 2.2581x; 2.2581x over previous
//
#include <hip/hip_runtime.h>
#include <math.h>

constexpr int B_ = 8;
constexpr int N_ = 2048;
constexpr int D_ = 128;
constexpr long long NDl = (long long)N_ * D_;     // 262144
constexpr long long NNl = (long long)N_ * N_;     // 4194304
constexpr float INV_TAU = 1.0f / 0.3f;
constexpr float SCALE_ = 20.0f;
constexpr float EPS_ = 1e-12f;

typedef __attribute__((ext_vector_type(8))) short short8;
typedef __attribute__((ext_vector_type(4))) float f32x4;
#define MFMA_BF16 __builtin_amdgcn_mfma_f32_16x16x32_bf16

// ---------------- workspace layout (float units) ----------------
constexpr size_t FL_F  = (size_t)B_ * NDl;   // 2097152
constexpr size_t FL_NN = (size_t)B_ * NNl;   // 33554432
constexpr size_t FL_V  = (size_t)B_ * N_;    // 16384

constexpr size_t OFF_SQ   = 0;
constexpr size_t OFF_ROWM = OFF_SQ   + FL_V;
constexpr size_t OFF_ROWZ = OFF_ROWM + FL_V;
constexpr size_t OFF_U0   = OFF_ROWZ + FL_V;
constexpr size_t OFF_V0   = OFF_U0   + FL_V;
constexpr size_t OFF_DIAG = OFF_V0   + FL_V;
constexpr size_t OFF_AV   = OFF_DIAG + FL_V;
constexpr size_t OFF_BV   = OFF_AV   + FL_V;
constexpr size_t OFF_ACC  = OFF_BV   + FL_V;      // 16 floats
constexpr size_t OFF_PM   = OFF_ACC  + 16;        // 32 chunks
constexpr size_t OFF_PS   = OFF_PM   + 32 * FL_V;
constexpr size_t OFF_PT   = OFF_PS   + 32 * FL_V; // 32 chunks
// aliases (time-disjoint): CP spans PM..PM+128*FL_V ; PCM/PCS inside PT
constexpr size_t OFF_CP   = OFF_PM;               // 128 stripes
constexpr size_t OFF_PCM  = OFF_PT;
constexpr size_t OFF_PCS  = OFF_PT + 16 * FL_V;
constexpr size_t OFF_C    = OFF_PM + 128 * FL_V;
constexpr size_t OFF_K    = OFF_C  + FL_NN;       // bf16 K (FL_NN ushort)
constexpr size_t OFF_BF   = OFF_K  + FL_NN / 2;   // 8 bf16 arrays, each FL_F ushorts
// total ≈ 244 MB (round-7 layout, proven to fit)

// ---------------- helpers ----------------
__device__ inline float bf2f(unsigned int lo16) {
  return __uint_as_float(lo16 << 16);
}
__device__ inline unsigned int f2bf(float x) {  // RNE bf16
  unsigned int u = __float_as_uint(x);
  u += 0x7fffu + ((u >> 16) & 1u);
  return (u >> 16) & 0xffffu;
}

// async global -> LDS, 16B per lane. lds dest = lbase + lane*16 (HW semantics).
__device__ inline void gload16(const unsigned short* g, unsigned short* lbase, int lane) {
#if defined(__has_builtin)
#if __has_builtin(__builtin_amdgcn_global_load_lds)
  __builtin_amdgcn_global_load_lds(
      (const __attribute__((address_space(1))) unsigned int*)g,
      (__attribute__((address_space(3))) unsigned int*)lbase, 16, 0, 0);
  return;
#endif
#endif
  *(uint4*)(lbase + lane * 8) = *(const uint4*)g;  // fallback
}

// ---------------- normalize: write split-bf16 f1/f2 ----------------
__global__ __launch_bounds__(64) void k_norm(const float* __restrict__ feats,
                                             unsigned short* __restrict__ f1hi,
                                             unsigned short* __restrict__ f1lo,
                                             unsigned short* __restrict__ f2hi,
                                             unsigned short* __restrict__ f2lo) {
  int r = blockIdx.x, b = blockIdx.y, which = blockIdx.z;
  const float* src = feats + ((size_t)(2 * b + which)) * NDl + (size_t)r * D_;
  int t = threadIdx.x;
  float2 x = *(const float2*)(src + 2 * t);
  float ss = x.x * x.x + x.y * x.y;
#pragma unroll
  for (int off = 32; off; off >>= 1) ss += __shfl_down(ss, off);
  ss = __shfl(ss, 0);
  float s = SCALE_ / fmaxf(sqrtf(ss), EPS_);
  float y0 = x.x * s, y1 = x.y * s;
  unsigned int h0 = f2bf(y0), h1 = f2bf(y1);
  unsigned int l0 = f2bf(y0 - bf2f(h0)), l1 = f2bf(y1 - bf2f(h1));
  size_t o = (size_t)b * NDl + (size_t)r * D_ + 2 * t;
  unsigned short* hb = (which ? f2hi : f1hi);
  unsigned short* lb = (which ? f2lo : f1lo);
  *(unsigned int*)(hb + o) = h0 | (h1 << 16);
  *(unsigned int*)(lb + o) = l0 | (l1 << 16);
}

// ---------------- transpose f1 -> f1t ([b][N][D] -> [b][D][N]) ----------------
__global__ __launch_bounds__(256) void k_transpose(const unsigned short* __restrict__ hi,
                                                   const unsigned short* __restrict__ lo,
                                                   unsigned short* __restrict__ thi,
                                                   unsigned short* __restrict__ tlo) {
  __shared__ unsigned short tile[64][66];
  int rt = blockIdx.x, dt = blockIdx.y, z = blockIdx.z;
  int b = z >> 1;
  const unsigned short* s = ((z & 1) ? lo : hi) + (size_t)b * NDl;
  unsigned short* d = ((z & 1) ? tlo : thi) + (size_t)b * NDl;
  int t = threadIdx.x;
  int r = t >> 2, c0 = (t & 3) * 16;
#pragma unroll
  for (int h = 0; h < 2; ++h) {
    uint4 v = *(const uint4*)(s + (size_t)(rt * 64 + r) * D_ + dt * 64 + c0 + h * 8);
    unsigned short* p = &tile[r][c0 + h * 8];
    p[0] = (unsigned short)v.x; p[1] = (unsigned short)(v.x >> 16);
    p[2] = (unsigned short)v.y; p[3] = (unsigned short)(v.y >> 16);
    p[4] = (unsigned short)v.z; p[5] = (unsigned short)(v.z >> 16);
    p[6] = (unsigned short)v.w; p[7] = (unsigned short)(v.w >> 16);
  }
  __syncthreads();
  int dd = t >> 2, r0 = (t & 3) * 16;
#pragma unroll
  for (int h = 0; h < 2; ++h) {
    unsigned int q[4];
#pragma unroll
    for (int e = 0; e < 4; ++e) {
      unsigned short a0 = tile[r0 + h * 8 + 2 * e][dd];
      unsigned short a1 = tile[r0 + h * 8 + 2 * e + 1][dd];
      q[e] = (unsigned int)a0 | ((unsigned int)a1 << 16);
    }
    uint4 v; v.x = q[0]; v.y = q[1]; v.z = q[2]; v.w = q[3];
    *(uint4*)(d + (size_t)(dt * 64 + dd) * N_ + rt * 64 + r0 + h * 8) = v;
  }
}

// ---------------- |x|^2 ----------------
__global__ __launch_bounds__(256) void k_sq(const float* __restrict__ pc0,
                                            float* __restrict__ sq) {
  int i = blockIdx.x * 256 + threadIdx.x;
  if (i < B_ * N_) {
    float x = pc0[3 * i], y = pc0[3 * i + 1], z = pc0[3 * i + 2];
    sq[i] = x * x + y * y + z * z;
  }
}

// ---------------- MFMA split-bf16: C = A @ B^T + fused row stats ----------------
template<bool WRITEC, bool TAU, bool SD, bool DIAG>
__global__ __launch_bounds__(256, 2) void k_mm(
    const unsigned short* __restrict__ Ahi_g, const unsigned short* __restrict__ Alo_g,
    const unsigned short* __restrict__ Bhi_g, const unsigned short* __restrict__ Blo_g,
    float* __restrict__ Cb, int roll,
    float* __restrict__ pms, float* __restrict__ pss, float* __restrict__ pts,
    float* __restrict__ diagb,
    const float* __restrict__ pc0, const float* __restrict__ sqv) {
  int bm = blockIdx.x, bn = blockIdx.y, z = blockIdx.z;
  int zb = (z + roll) & 7;
  const unsigned short* A_hi = Ahi_g + (size_t)z * NDl;
  const unsigned short* A_lo = Alo_g + (size_t)z * NDl;
  const unsigned short* B_hi = Bhi_g + (size_t)zb * NDl;
  const unsigned short* B_lo = Blo_g + (size_t)zb * NDl;
  float* C = Cb + (size_t)z * NNl;

  __shared__ __align__(16) unsigned short sAh[128 * 64], sAl[128 * 64];
  __shared__ __align__(16) unsigned short sBh[128 * 64], sBl[128 * 64];
  __shared__ float rpx[128], rpy[128], rpz[128], rps[128];
  __shared__ float cqx[128], cqy[128], cqz[128], cqs[128];

  int t = threadIdx.x;
  int lane = t & 63, w = t >> 6;
  int wm = w >> 1, wn = w & 1;

  if constexpr (SD) {
    const float* xb = pc0 + (size_t)z * N_ * 3;
    const float* sb = sqv + (size_t)z * N_;
    if (t < 128) {
      int r = bm * 128 + t;
      rpx[t] = xb[3 * r]; rpy[t] = xb[3 * r + 1]; rpz[t] = xb[3 * r + 2]; rps[t] = sb[r];
    } else {
      int c = bn * 128 + (t - 128);
      cqx[t - 128] = xb[3 * c]; cqy[t - 128] = xb[3 * c + 1]; cqz[t - 128] = xb[3 * c + 2];
      cqs[t - 128] = sb[c];
    }
  }

  f32x4 acc[4][4] = {};

  for (int kc = 0; kc < D_; kc += 64) {
    if (kc) __syncthreads();
#pragma unroll
    for (int i = 0; i < 4; ++i) {
      int li = i * 256 + t;
      int r = li >> 3;            // 0..127
      int j = li & 7;             // 16B block in row
      int xoff = (j * 8) ^ ((r & 7) << 3);   // swizzled source offset (ushorts)
      size_t grow_a = (size_t)(bm * 128 + r) * D_ + kc + xoff;
      size_t grow_b = (size_t)(bn * 128 + r) * D_ + kc + xoff;
      int wbase = (i * 256 + (t & 192)) * 8; // wave-uniform linear LDS base (ushorts)
      gload16(A_hi + grow_a, &sAh[wbase], lane);
      gload16(A_lo + grow_a, &sAl[wbase], lane);
      gload16(B_hi + grow_b, &sBh[wbase], lane);
      gload16(B_lo + grow_b, &sBl[wbase], lane);
    }
    __syncthreads();

    short8 ah[4][2], al[4][2];
#pragma unroll
    for (int m = 0; m < 4; ++m)
#pragma unroll
      for (int ks = 0; ks < 2; ++ks) {
        int row = wm * 64 + m * 16 + (lane & 15);
        int kb = ks * 64 + ((lane >> 4) * 16);
        int idx = (row * 128 + (kb ^ ((row & 7) << 4))) >> 1;
        ah[m][ks] = *(const short8*)(&sAh[idx]);
        al[m][ks] = *(const short8*)(&sAl[idx]);
      }
#pragma unroll
    for (int n = 0; n < 4; ++n) {
#pragma unroll
      for (int ks = 0; ks < 2; ++ks) {
        int row = wn * 64 + n * 16 + (lane & 15);
        int kb = ks * 64 + ((lane >> 4) * 16);
        int idx = (row * 128 + (kb ^ ((row & 7) << 4))) >> 1;
        short8 bh = *(const short8*)(&sBh[idx]);
        short8 bl = *(const short8*)(&sBl[idx]);
#pragma unroll
        for (int m = 0; m < 4; ++m) {
          acc[m][n] = MFMA_BF16(ah[m][ks], bh, acc[m][n], 0, 0, 0);
          acc[m][n] = MFMA_BF16(ah[m][ks], bl, acc[m][n], 0, 0, 0);
          acc[m][n] = MFMA_BF16(al[m][ks], bh, acc[m][n], 0, 0, 0);
        }
      }
    }
  }

  int lrow = (lane >> 4) * 4;
  int lcol = lane & 15;

  if constexpr (WRITEC) {
#pragma unroll
    for (int m = 0; m < 4; ++m) {
      int gr0 = bm * 128 + wm * 64 + m * 16 + lrow;
#pragma unroll
      for (int n = 0; n < 4; ++n) {
        int gc = bn * 128 + wn * 64 + n * 16 + lcol;
        float* Cp = C + (size_t)gr0 * N_ + gc;
#pragma unroll
        for (int rg = 0; rg < 4; ++rg)
          Cp[(size_t)rg * N_] = acc[m][n][rg];
      }
    }
  }

  // per-row stats over this wave's 64 cols -> chunk (bn*2+wn)
#pragma unroll
  for (int m = 0; m < 4; ++m) {
#pragma unroll
    for (int rg = 0; rg < 4; ++rg) {
      int rib = wm * 64 + m * 16 + lrow + rg;
      float v0 = acc[m][0][rg], v1 = acc[m][1][rg], v2 = acc[m][2][rg], v3 = acc[m][3][rg];
      float mx = fmaxf(fmaxf(v0, v1), fmaxf(v2, v3));
#pragma unroll
      for (int msk = 1; msk < 16; msk <<= 1) mx = fmaxf(mx, __shfl_xor(mx, msk));
      float e0 = __expf(v0 - mx), e1 = __expf(v1 - mx), e2 = __expf(v2 - mx), e3 = __expf(v3 - mx);
      float s = e0 + e1 + e2 + e3;
      float st = 0.f, sd = 0.f;
      if constexpr (TAU)
        st = __expf((v0 - mx) * INV_TAU) + __expf((v1 - mx) * INV_TAU) +
             __expf((v2 - mx) * INV_TAU) + __expf((v3 - mx) * INV_TAU);
      if constexpr (SD) {
        float xi = rpx[rib], yi = rpy[rib], zi = rpz[rib], si = rps[rib];
#pragma unroll
        for (int n = 0; n < 4; ++n) {
          int ci = wn * 64 + n * 16 + lcol;
          float d2 = fmaxf(si + cqs[ci] - 2.f * (xi * cqx[ci] + yi * cqy[ci] + zi * cqz[ci]), 0.f);
          float en = (n == 0) ? e0 : (n == 1) ? e1 : (n == 2) ? e2 : e3;
          sd += en * sqrtf(sqrtf(d2));
        }
      }
#pragma unroll
      for (int msk = 1; msk < 16; msk <<= 1) {
        s += __shfl_xor(s, msk);
        if constexpr (TAU) st += __shfl_xor(st, msk);
        if constexpr (SD) sd += __shfl_xor(sd, msk);
      }
      if (lcol == 0) {
        size_t idx = ((size_t)(z * 32 + bn * 2 + wn)) * N_ + bm * 128 + rib;
        pms[idx] = mx; pss[idx] = s;
        if constexpr (TAU) pts[idx] = st;
        if constexpr (SD) pts[idx] = sd;
      }
    }
  }

  if constexpr (DIAG) {
    if (bm == bn && wm == wn) {
#pragma unroll
      for (int m = 0; m < 4; ++m)
#pragma unroll
        for (int rg = 0; rg < 4; ++rg) {
          int rr = lrow + rg;
          if (lcol == rr)
            diagb[(size_t)z * N_ + bm * 128 + wm * 64 + m * 16 + rr] = acc[m][m][rg];
        }
    }
  }
}

// ---------------- combine tile stats -> rowm/rowZ/u0 + scalar accumulations ----------------
template<bool WMZ, bool TAU, bool SD, bool DIAG, bool MATCH>
__global__ __launch_bounds__(256) void k_comb(const float* __restrict__ pms,
                                              const float* __restrict__ pss,
                                              const float* __restrict__ pts,
                                              const float* __restrict__ diagb,
                                              float* __restrict__ rowm,
                                              float* __restrict__ rowZ,
                                              float* __restrict__ u0,
                                              float* __restrict__ acc) {
  int b = blockIdx.y;
  int r = blockIdx.x * 256 + threadIdx.x;
  float M = -INFINITY, S = 0.f, ST = 0.f, SDa = 0.f;
#pragma unroll
  for (int p = 0; p < 32; ++p) {
    size_t idx = ((size_t)(b * 32 + p)) * N_ + r;
    float m = pms[idx], s = pss[idx];
    float M2 = fmaxf(M, m);
    float f0 = __expf(M - M2), f1 = __expf(m - M2);
    S = S * f0 + s * f1;
    if constexpr (TAU) ST = ST * __expf((M - M2) * INV_TAU) + pts[idx] * __expf((m - M2) * INV_TAU);
    if constexpr (SD)  SDa = SDa * f0 + pts[idx] * f1;
    M = M2;
  }
  size_t vr = (size_t)b * N_ + r;
  if constexpr (WMZ) { rowm[vr] = M; rowZ[vr] = S; }
  if constexpr (TAU) u0[vr] = M * INV_TAU + __logf(ST);
  float contrib = 0.f; int slot = -1;
  if constexpr (SD)    { contrib = SDa / S; slot = 0; }
  if constexpr (DIAG)  { contrib = __expf(diagb[vr] - M) / S; slot = 3; }
  if constexpr (MATCH) { contrib = (diagb[vr] == M) ? 1.f : 0.f; slot = 4; }
  if (slot >= 0) {
    __shared__ float red[256];
    int t = threadIdx.x;
    red[t] = contrib; __syncthreads();
    for (int off = 128; off; off >>= 1) { if (t < off) red[t] += red[t + off]; __syncthreads(); }
    if (t == 0) atomicAdd(acc + slot, red[0]);
  }
}

// ---------------- MFMA: Out = softmax(C) @ W (BM=64, 256 blocks, 3/CU) ----------------
__global__ __launch_bounds__(256, 3) void k_smmm(
    const float* __restrict__ Cb, const float* __restrict__ rowm, const float* __restrict__ rowZ,
    const unsigned short* __restrict__ Wthi, const unsigned short* __restrict__ Wtlo,
    unsigned short* __restrict__ Ohi, unsigned short* __restrict__ Olo, int roll) {
  int bm = blockIdx.x, z = blockIdx.y;   // bm in 0..31
  int zb = (z + roll) & 7;
  const float* C = Cb + (size_t)z * NNl + (size_t)(bm * 64) * N_;
  const unsigned short* Wh = Wthi + (size_t)zb * NDl;
  const unsigned short* Wl = Wtlo + (size_t)zb * NDl;

  __shared__ __align__(16) unsigned short sPh[64 * 64], sPl[64 * 64];
  __shared__ __align__(16) unsigned short sWh[128 * 64], sWl[128 * 64];
  __shared__ float s_rm[64], s_rz[64];

  int t = threadIdx.x, lane = t & 63, w = t >> 6;
  if (t < 64) {
    s_rm[t] = rowm[(size_t)z * N_ + bm * 64 + t];
    s_rz[t] = rowZ[(size_t)z * N_ + bm * 64 + t];
  }
  __syncthreads();

  f32x4 acc[8] = {};

  for (int jc = 0; jc < N_; jc += 64) {
    if (jc) __syncthreads();
    // P staging (compute exp + split), 64 rows x 64 j
#pragma unroll
    for (int i = 0; i < 4; ++i) {
      int li = i * 256 + t;
      int r = li >> 4;
      int j4 = (li & 15) * 4;
      float4 c4 = *(const float4*)(C + (size_t)r * N_ + jc + j4);
      float rm = s_rm[r];
      float p0 = __expf(c4.x - rm), p1 = __expf(c4.y - rm);
      float p2 = __expf(c4.z - rm), p3 = __expf(c4.w - rm);
      unsigned int h0 = f2bf(p0), h1 = f2bf(p1), h2 = f2bf(p2), h3 = f2bf(p3);
      unsigned int l0 = f2bf(p0 - bf2f(h0)), l1 = f2bf(p1 - bf2f(h1));
      unsigned int l2 = f2bf(p2 - bf2f(h2)), l3 = f2bf(p3 - bf2f(h3));
      int kb = j4 * 2;
      int sidx = (r * 128 + (kb ^ ((r & 7) << 4))) >> 1;
      uint2 ph; ph.x = h0 | (h1 << 16); ph.y = h2 | (h3 << 16);
      uint2 pl; pl.x = l0 | (l1 << 16); pl.y = l2 | (l3 << 16);
      *(uint2*)(&sPh[sidx]) = ph;
      *(uint2*)(&sPl[sidx]) = pl;
    }
    // W staging (pre-transposed bf16) via global_load_lds, linear dest + swizzled src
#pragma unroll
    for (int i = 0; i < 4; ++i) {
      int li = i * 256 + t;
      int d = li >> 3;
      int j = li & 7;
      int xoff = (j * 8) ^ ((d & 7) << 3);
      size_t ga = (size_t)d * N_ + jc + xoff;
      int wbase = (i * 256 + (t & 192)) * 8;
      gload16(Wh + ga, &sWh[wbase], lane);
      gload16(Wl + ga, &sWl[wbase], lane);
    }
    __syncthreads();

    short8 ph[2], pl[2];
#pragma unroll
    for (int ks = 0; ks < 2; ++ks) {
      int row = w * 16 + (lane & 15);
      int kb = ks * 64 + ((lane >> 4) * 16);
      int idx = (row * 128 + (kb ^ ((row & 7) << 4))) >> 1;
      ph[ks] = *(const short8*)(&sPh[idx]);
      pl[ks] = *(const short8*)(&sPl[idx]);
    }
#pragma unroll
    for (int n = 0; n < 8; ++n) {
#pragma unroll
      for (int ks = 0; ks < 2; ++ks) {
        int row = n * 16 + (lane & 15);
        int kb = ks * 64 + ((lane >> 4) * 16);
        int idx = (row * 128 + (kb ^ ((row & 7) << 4))) >> 1;
        short8 bh = *(const short8*)(&sWh[idx]);
        short8 bl = *(const short8*)(&sWl[idx]);
        acc[n] = MFMA_BF16(ph[ks], bh, acc[n], 0, 0, 0);
        acc[n] = MFMA_BF16(ph[ks], bl, acc[n], 0, 0, 0);
        acc[n] = MFMA_BF16(pl[ks], bh, acc[n], 0, 0, 0);
      }
    }
  }

  // epilogue: /Z, split bf16, store
  unsigned short* OhB = Ohi + (size_t)z * NDl;
  unsigned short* OlB = Olo + (size_t)z * NDl;
#pragma unroll
  for (int rg = 0; rg < 4; ++rg) {
    int rib = w * 16 + (lane >> 4) * 4 + rg;
    float iZ = 1.f / s_rz[rib];
    size_t ro = (size_t)(bm * 64 + rib) * D_;
#pragma unroll
    for (int n = 0; n < 8; ++n) {
      int d = n * 16 + (lane & 15);
      float vv = acc[n][rg] * iZ;
      unsigned int h = f2bf(vv);
      OhB[ro + d] = (unsigned short)h;
      OlB[ro + d] = (unsigned short)f2bf(vv - bf2f(h));
    }
  }
}

// ---------------- col LSE of (C/tau - u0) -> partials ----------------
__global__ __launch_bounds__(256) void k_colLSE(const float* __restrict__ Cb,
                                                const float* __restrict__ u0,
                                                float* __restrict__ pcm,
                                                float* __restrict__ pcs) {
  int jb = blockIdx.x, ch = blockIdx.y, b = blockIdx.z;
  int t = threadIdx.x;
  int j4 = (jb * 256 + t) * 4;
  __shared__ float su[128];
  if (t < 128) su[t] = u0[(size_t)b * N_ + ch * 128 + t];
  __syncthreads();
  const float* Cp = Cb + (size_t)b * NNl + (size_t)(ch * 128) * N_ + j4;
  float m0 = -INFINITY, m1 = -INFINITY, m2 = -INFINITY, m3 = -INFINITY;
  float s0 = 0.f, s1 = 0.f, s2 = 0.f, s3 = 0.f;
#pragma unroll 4
  for (int i = 0; i < 128; ++i) {
    float4 c = *(const float4*)(Cp + (size_t)i * N_);
    float ui = su[i];
    float x0 = c.x * INV_TAU - ui, x1 = c.y * INV_TAU - ui;
    float x2 = c.z * INV_TAU - ui, x3 = c.w * INV_TAU - ui;
    float M0 = fmaxf(m0, x0); s0 = s0 * __expf(m0 - M0) + __expf(x0 - M0); m0 = M0;
    float M1 = fmaxf(m1, x1); s1 = s1 * __expf(m1 - M1) + __expf(x1 - M1); m1 = M1;
    float M2 = fmaxf(m2, x2); s2 = s2 * __expf(m2 - M2) + __expf(x2 - M2); m2 = M2;
    float M3 = fmaxf(m3, x3); s3 = s3 * __expf(m3 - M3) + __expf(x3 - M3); m3 = M3;
  }
  size_t o = ((size_t)(b * 16 + ch)) * N_ + j4;
  float4 vm; vm.x = m0; vm.y = m1; vm.z = m2; vm.w = m3;
  float4 vs; vs.x = s0; vs.y = s1; vs.z = s2; vs.w = s3;
  *(float4*)(pcm + o) = vm;
  *(float4*)(pcs + o) = vs;
}

__global__ __launch_bounds__(256) void k_colLSEcomb(const float* __restrict__ pcm,
                                                    const float* __restrict__ pcs,
                                                    float* __restrict__ v0) {
  int b = blockIdx.y; int j = blockIdx.x * 256 + threadIdx.x;
  float m = -INFINITY, s = 0.f;
#pragma unroll
  for (int ch = 0; ch < 16; ++ch) {
    size_t idx = ((size_t)(b * 16 + ch)) * N_ + j;
    float m2 = pcm[idx], s2 = pcs[idx];
    float M = fmaxf(m, m2);
    s = s * __expf(m - M) + s2 * __expf(m2 - M);
    m = M;
  }
  v0[(size_t)b * N_ + j] = m + __logf(s);
}

// ---------------- sinkhorn init: read C, write K, first linear iter ----------------
__global__ __launch_bounds__(256) void k_sink_init(const float* __restrict__ Cb,
                                                   unsigned short* __restrict__ Kp,
                                                   const float* __restrict__ u0,
                                                   const float* __restrict__ v0,
                                                   float* __restrict__ avec,
                                                   float* __restrict__ cp) {
  int stripe = blockIdx.x, b = blockIdx.y;   // stripe 0..127
  int i0 = stripe * 16;
  int t = threadIdx.x;
  int w = t >> 6, l = t & 63;
  __shared__ float a_s[16];
  float bv[4][8];
  const float* vsrc = v0 + (size_t)b * N_;
#pragma unroll
  for (int c = 0; c < 4; ++c) {
    float4 q0 = *(const float4*)(vsrc + c * 512 + l * 8);
    float4 q1 = *(const float4*)(vsrc + c * 512 + l * 8 + 4);
    bv[c][0] = q0.x; bv[c][1] = q0.y; bv[c][2] = q0.z; bv[c][3] = q0.w;
    bv[c][4] = q1.x; bv[c][5] = q1.y; bv[c][6] = q1.z; bv[c][7] = q1.w;
  }
  unsigned short* Kb = Kp + (size_t)b * NNl;
  const float* Cbb = Cb + (size_t)b * NNl;
#pragma unroll
  for (int ii = 0; ii < 4; ++ii) {
    int i = w * 4 + ii;
    int row = i0 + i;
    float r = 0.f;
    float ub = u0[(size_t)b * N_ + row];
    const float* Crow = Cbb + (size_t)row * N_;
    unsigned short* Krow = Kb + (size_t)row * N_;
#pragma unroll
    for (int c = 0; c < 4; ++c) {
      float4 c0 = *(const float4*)(Crow + c * 512 + l * 8);
      float4 c1 = *(const float4*)(Crow + c * 512 + l * 8 + 4);
      float cv[8] = {c0.x, c0.y, c0.z, c0.w, c1.x, c1.y, c1.z, c1.w};
      float kv[8];
#pragma unroll
      for (int e = 0; e < 8; ++e) { kv[e] = __expf(cv[e] * INV_TAU - ub - bv[c][e]); r += kv[e]; }
      uint4 pk;
      pk.x = f2bf(kv[0]) | (f2bf(kv[1]) << 16);
      pk.y = f2bf(kv[2]) | (f2bf(kv[3]) << 16);
      pk.z = f2bf(kv[4]) | (f2bf(kv[5]) << 16);
      pk.w = f2bf(kv[6]) | (f2bf(kv[7]) << 16);
      *(uint4*)(Krow + c * 512 + l * 8) = pk;
    }
#pragma unroll
    for (int off = 1; off < 64; off <<= 1) r += __shfl_xor(r, off);
    if (l == 0) {
      float a = 1.f / r;
      a_s[i] = a;
      avec[(size_t)b * N_ + row] = a;
    }
  }
  __threadfence_block();
  __syncthreads();
  float cpa[8] = {};
  const unsigned short* Kc = Kb + (size_t)i0 * N_ + w * 512 + l * 8;
#pragma unroll 4
  for (int i = 0; i < 16; ++i) {
    uint4 pk = *(const uint4*)(Kc + (size_t)i * N_);
    float ai = a_s[i];
    cpa[0] += bf2f(pk.x & 0xffffu) * ai; cpa[1] += bf2f(pk.x >> 16) * ai;
    cpa[2] += bf2f(pk.y & 0xffffu) * ai; cpa[3] += bf2f(pk.y >> 16) * ai;
    cpa[4] += bf2f(pk.z & 0xffffu) * ai; cpa[5] += bf2f(pk.z >> 16) * ai;
    cpa[6] += bf2f(pk.w & 0xffffu) * ai; cpa[7] += bf2f(pk.w >> 16) * ai;
  }
  size_t o = ((size_t)(b * 128 + stripe)) * N_ + w * 512 + l * 8;
  float4 o0; o0.x = cpa[0]; o0.y = cpa[1]; o0.z = cpa[2]; o0.w = cpa[3];
  float4 o1; o1.x = cpa[4]; o1.y = cpa[5]; o1.z = cpa[6]; o1.w = cpa[7];
  *(float4*)(cp + o) = o0;
  *(float4*)(cp + o + 4) = o1;
}

// ---------------- sinkhorn linear iteration, LDS-staged in two 8-row halves ----------
// 32 KB LDS -> 4 blocks/CU (vs round-7's 64 KB / 2 blocks). Same cp layout.
__global__ __launch_bounds__(256) void k_sink_iterL(const unsigned short* __restrict__ Kp,
                                                    const float* __restrict__ bvec,
                                                    float* __restrict__ avec,
                                                    float* __restrict__ cp) {
  int stripe = blockIdx.x, b = blockIdx.y;   // stripe 0..127 (16 rows each)
  int i0 = stripe * 16;
  int t = threadIdx.x;
  int w = t >> 6, l = t & 63;
  __shared__ __align__(16) unsigned short sK[8 * 2048];  // 32 KB half-stripe
  __shared__ float a_s[8];
  const unsigned short* Kb = Kp + (size_t)b * NNl + (size_t)i0 * N_;
  float bv[4][8];
  const float* vsrc = bvec + (size_t)b * N_;
#pragma unroll
  for (int c = 0; c < 4; ++c) {
    float4 q0 = *(const float4*)(vsrc + c * 512 + l * 8);
    float4 q1 = *(const float4*)(vsrc + c * 512 + l * 8 + 4);
    bv[c][0] = q0.x; bv[c][1] = q0.y; bv[c][2] = q0.z; bv[c][3] = q0.w;
    bv[c][4] = q1.x; bv[c][5] = q1.y; bv[c][6] = q1.z; bv[c][7] = q1.w;
  }
  float cpa[8] = {};
  for (int h = 0; h < 2; ++h) {
    if (h) __syncthreads();   // previous half's phase2 done before overwriting sK/a_s
    // stage 8 rows (32 KB): 2048 chunks of 16B, 8 gloads/thread, linear dest=src
#pragma unroll
    for (int i = 0; i < 8; ++i) {
      int li = i * 256 + t;              // 0..2047
      int wbase = (li & ~63) * 8;        // wave-uniform LDS base (ushorts)
      gload16(Kb + (size_t)(h * 8) * N_ + (size_t)li * 8, &sK[wbase], l);
    }
    __syncthreads();   // drains global_load_lds
    // phase 1: wave w dots local rows 2w, 2w+1
#pragma unroll
    for (int rr = 0; rr < 2; ++rr) {
      int lr = w * 2 + rr;
      float r = 0.f;
#pragma unroll
      for (int c = 0; c < 4; ++c) {
        uint4 pk = *(const uint4*)(&sK[lr * 2048 + c * 512 + l * 8]);
        r += bf2f(pk.x & 0xffffu) * bv[c][0] + bf2f(pk.x >> 16) * bv[c][1]
           + bf2f(pk.y & 0xffffu) * bv[c][2] + bf2f(pk.y >> 16) * bv[c][3]
           + bf2f(pk.z & 0xffffu) * bv[c][4] + bf2f(pk.z >> 16) * bv[c][5]
           + bf2f(pk.w & 0xffffu) * bv[c][6] + bf2f(pk.w >> 16) * bv[c][7];
      }
#pragma unroll
      for (int off = 1; off < 64; off <<= 1) r += __shfl_xor(r, off);
      if (l == 0) {
        float a = 1.f / r;
        a_s[lr] = a;
        avec[(size_t)b * N_ + i0 + h * 8 + lr] = a;
      }
    }
    __syncthreads();
    // phase 2: thread t owns cols 8t..8t+7 over the 8 half rows
#pragma unroll
    for (int i = 0; i < 8; ++i) {
      uint4 pk = *(const uint4*)(&sK[i * 2048 + t * 8]);
      float ai = a_s[i];
      cpa[0] += bf2f(pk.x & 0xffffu) * ai; cpa[1] += bf2f(pk.x >> 16) * ai;
      cpa[2] += bf2f(pk.y & 0xffffu) * ai; cpa[3] += bf2f(pk.y >> 16) * ai;
      cpa[4] += bf2f(pk.z & 0xffffu) * ai; cpa[5] += bf2f(pk.z >> 16) * ai;
      cpa[6] += bf2f(pk.w & 0xffffu) * ai; cpa[7] += bf2f(pk.w >> 16) * ai;
    }
  }
  size_t o = ((size_t)(b * 128 + stripe)) * N_ + t * 8;
  float4 o0; o0.x = cpa[0]; o0.y = cpa[1]; o0.z = cpa[2]; o0.w = cpa[3];
  float4 o1; o1.x = cpa[4]; o1.y = cpa[5]; o1.z = cpa[6]; o1.w = cpa[7];
  *(float4*)(cp + o) = o0;
  *(float4*)(cp + o + 4) = o1;
}

__global__ __launch_bounds__(256) void k_bcomb(const float* __restrict__ cp,
                                               float* __restrict__ bvec) {
  int b = blockIdx.y; int j = blockIdx.x * 256 + threadIdx.x;
  float s0 = 0.f, s1 = 0.f, s2 = 0.f, s3 = 0.f;
#pragma unroll 8
  for (int st = 0; st < 128; st += 4) {
    s0 += cp[((size_t)(b * 128 + st + 0)) * N_ + j];
    s1 += cp[((size_t)(b * 128 + st + 1)) * N_ + j];
    s2 += cp[((size_t)(b * 128 + st + 2)) * N_ + j];
    s3 += cp[((size_t)(b * 128 + st + 3)) * N_ + j];
  }
  bvec[(size_t)b * N_ + j] = 1.f / ((s0 + s1) + (s2 + s3));
}

// ---------------- final fused elementwise ----------------
__global__ __launch_bounds__(256) void k_felem(const float* __restrict__ Cb,
                                               const unsigned short* __restrict__ Kp,
                                               const float* __restrict__ rowm,
                                               const float* __restrict__ rowZ,
                                               const float* __restrict__ avec,
                                               const float* __restrict__ bvec,
                                               const float* __restrict__ pc0,
                                               const float* __restrict__ sqv,
                                               float* __restrict__ acc) {
  int rb = blockIdx.x, b = blockIdx.y;
  int i0 = rb * 16;
  int t = threadIdx.x;
  const float* xb = pc0 + (size_t)b * N_ * 3;
  const float* sqb = sqv + (size_t)b * N_;
  float xj[2][4], yj[2][4], zj[2][4], sj[2][4], bj[2][4];
#pragma unroll
  for (int kk = 0; kk < 2; ++kk) {
    int j4 = t * 4 + kk * 1024;
    float4 p0 = *(const float4*)(xb + 3 * j4);
    float4 p1 = *(const float4*)(xb + 3 * j4 + 4);
    float4 p2 = *(const float4*)(xb + 3 * j4 + 8);
    xj[kk][0] = p0.x; yj[kk][0] = p0.y; zj[kk][0] = p0.z;
    xj[kk][1] = p0.w; yj[kk][1] = p1.x; zj[kk][1] = p1.y;
    xj[kk][2] = p1.z; yj[kk][2] = p1.w; zj[kk][2] = p2.x;
    xj[kk][3] = p2.y; yj[kk][3] = p2.z; zj[kk][3] = p2.w;
    float4 s4 = *(const float4*)(sqb + j4);
    sj[kk][0] = s4.x; sj[kk][1] = s4.y; sj[kk][2] = s4.z; sj[kk][3] = s4.w;
    float4 b4 = *(const float4*)(bvec + (size_t)b * N_ + j4);
    bj[kk][0] = b4.x; bj[kk][1] = b4.y; bj[kk][2] = b4.z; bj[kk][3] = b4.w;
  }
  float aL = 0.f, aLc = 0.f, aP = 0.f;
  for (int ii = 0; ii < 16; ++ii) {
    int i = i0 + ii;
    float xi = xb[3 * i], yi = xb[3 * i + 1], zi = xb[3 * i + 2];
    float sqi = sqb[i];
    float mi = rowm[(size_t)b * N_ + i];
    float iZ = 1.f / rowZ[(size_t)b * N_ + i];
    float ai = avec[(size_t)b * N_ + i];
    const float* Crow = Cb + (size_t)b * NNl + (size_t)i * N_;
    const unsigned short* Krow = Kp + (size_t)b * NNl + (size_t)i * N_;
#pragma unroll
    for (int kk = 0; kk < 2; ++kk) {
      int j4 = t * 4 + kk * 1024;
      float4 c4 = *(const float4*)(Crow + j4);
      uint2 k2 = *(const uint2*)(Krow + j4);
      float kf[4] = { bf2f(k2.x & 0xffffu), bf2f(k2.x >> 16),
                      bf2f(k2.y & 0xffffu), bf2f(k2.y >> 16) };
      float cf[4] = { c4.x, c4.y, c4.z, c4.w };
#pragma unroll
      for (int e = 0; e < 4; ++e) {
        int j = j4 + e;
        float sm = __expf(cf[e] - mi) * iZ;
        float sink = kf[e] * ai * bj[kk][e];
        float d2 = fmaxf(sqi + sj[kk][e] - 2.f * (xi * xj[kk][e] + yi * yj[kk][e] + zi * zj[kk][e]), 0.f);
        aL += sqrtf(sqrtf(d2)) * sm;
        aLc += fabsf(sink - sm);
        aP += fabsf(((i == j) ? 1.f : 0.f) - sink);
      }
    }
  }
  __shared__ float red[256];
  red[t] = aL; __syncthreads();
  for (int off = 128; off; off >>= 1) { if (t < off) red[t] += red[t + off]; __syncthreads(); }
  if (t == 0) atomicAdd(acc + 0, red[0]);
  __syncthreads();
  red[t] = aLc; __syncthreads();
  for (int off = 128; off; off >>= 1) { if (t < off) red[t] += red[t + off]; __syncthreads(); }
  if (t == 0) atomicAdd(acc + 1, red[0]);
  __syncthreads();
  red[t] = aP; __syncthreads();
  for (int off = 128; off; off >>= 1) { if (t < off) red[t] += red[t + off]; __syncthreads(); }
  if (t == 0) atomicAdd(acc + 2, red[0]);
}

// ---------------- finalize ----------------
__global__ void k_finalize(const float* __restrict__ acc, float* __restrict__ out) {
  float invN = 1.0f / (float)N_;
  float L  = acc[0] * invN;
  float Lc = 3.f * acc[1] * invN;
  float P  = 3.f * acc[2] * invN;
  float Dg = -acc[3] * invN;
  float M  = acc[4];
  float invB = 1.0f / (float)B_;
  out[0] = (L + Lc) * invB;
  out[1] = L * invB;
  out[2] = Lc * invB;
  out[3] = P * invB;
  out[4] = M * invB;
  out[5] = Dg * invB;
}

extern "C" void kernel_launch(void* const* d_in, const int* in_sizes, int n_in,
                              void* d_out, int out_size, void* d_ws, size_t ws_size,
                              hipStream_t stream) {
  const float* feats = (const float*)d_in[0];
  const float* pc0 = (const float*)d_in[1];
  float* out = (float*)d_out;
  float* ws = (float*)d_ws;

  float* sqv   = ws + OFF_SQ;
  float* rowm  = ws + OFF_ROWM;
  float* rowZ  = ws + OFF_ROWZ;
  float* u0    = ws + OFF_U0;
  float* v0    = ws + OFF_V0;
  float* diagb = ws + OFF_DIAG;
  float* avec  = ws + OFF_AV;
  float* bvec  = ws + OFF_BV;
  float* acc   = ws + OFF_ACC;
  float* pms   = ws + OFF_PM;
  float* pss   = ws + OFF_PS;
  float* pts   = ws + OFF_PT;
  float* pcm   = ws + OFF_PCM;
  float* pcs   = ws + OFF_PCS;
  float* cp    = ws + OFF_CP;
  float* C     = ws + OFF_C;
  unsigned short* Kp = (unsigned short*)(ws + OFF_K);
  unsigned short* bfb = (unsigned short*)(ws + OFF_BF);
  unsigned short* f1hi   = bfb + 0 * FL_F;
  unsigned short* f1lo   = bfb + 1 * FL_F;
  unsigned short* f2hi   = bfb + 2 * FL_F;
  unsigned short* f2lo   = bfb + 3 * FL_F;
  unsigned short* f1t_hi = bfb + 4 * FL_F;
  unsigned short* f1t_lo = bfb + 5 * FL_F;
  unsigned short* fvahi  = bfb + 6 * FL_F;
  unsigned short* fvalo  = bfb + 7 * FL_F;

  hipMemsetAsync(acc, 0, 16 * sizeof(float), stream);

  k_norm<<<dim3(N_, B_, 2), 64, 0, stream>>>(feats, f1hi, f1lo, f2hi, f2lo);
  k_transpose<<<dim3(32, 2, 16), 256, 0, stream>>>(f1hi, f1lo, f1t_hi, f1t_lo);
  k_sq<<<(B_ * N_) / 256, 256, 0, stream>>>(pc0, sqv);

  dim3 mmGrid(N_ / 128, N_ / 128, B_);
  dim3 cbGrid(N_ / 256, B_);
  dim3 smGrid(N_ / 64, B_);

  // g-branch: fv = softmax(f1 f1^T) @ f1 ; d = -sum diag softmax(fv f1^T)
  k_mm<true, false, false, false><<<mmGrid, 256, 0, stream>>>(f1hi, f1lo, f1hi, f1lo, C, 0, pms, pss, pts, diagb, pc0, sqv);
  k_comb<true, false, false, false, false><<<cbGrid, 256, 0, stream>>>(pms, pss, pts, diagb, rowm, rowZ, u0, acc);
  k_smmm<<<smGrid, 256, 0, stream>>>(C, rowm, rowZ, f1t_hi, f1t_lo, fvahi, fvalo, 0);
  k_mm<false, false, false, true><<<mmGrid, 256, 0, stream>>>(fvahi, fvalo, f1hi, f1lo, C, 0, pms, pss, pts, diagb, pc0, sqv);
  k_comb<false, false, false, true, false><<<cbGrid, 256, 0, stream>>>(pms, pss, pts, diagb, rowm, rowZ, u0, acc);

  // corr_12 = f1 @ f2^T : loss term 2 (dist-weighted partials, no C write)
  k_mm<false, false, true, false><<<mmGrid, 256, 0, stream>>>(f1hi, f1lo, f2hi, f2lo, C, 0, pms, pss, pts, diagb, pc0, sqv);
  k_comb<false, false, true, false, false><<<cbGrid, 256, 0, stream>>>(pms, pss, pts, diagb, rowm, rowZ, u0, acc);

  // corr_1a = f1 @ fa^T ; f1_via_fa_t = softmax @ fa
  k_mm<true, false, false, false><<<mmGrid, 256, 0, stream>>>(f1hi, f1lo, f1hi, f1lo, C, 1, pms, pss, pts, diagb, pc0, sqv);
  k_comb<true, false, false, false, false><<<cbGrid, 256, 0, stream>>>(pms, pss, pts, diagb, rowm, rowZ, u0, acc);
  k_smmm<<<smGrid, 256, 0, stream>>>(C, rowm, rowZ, f1t_hi, f1t_lo, fvahi, fvalo, 1);

  // corr_1a2 = f1_via_fa_t @ f2^T : stats + tau-LSE + diag(match)
  k_mm<true, true, false, true><<<mmGrid, 256, 0, stream>>>(fvahi, fvalo, f2hi, f2lo, C, 0, pms, pss, pts, diagb, pc0, sqv);
  k_comb<true, true, false, false, true><<<cbGrid, 256, 0, stream>>>(pms, pss, pts, diagb, rowm, rowZ, u0, acc);

  // sinkhorn: log-domain first iteration (u0, v0), then linear iterations on bf16 K
  k_colLSE<<<dim3(2, 16, B_), 256, 0, stream>>>(C, u0, pcm, pcs);
  k_colLSEcomb<<<cbGrid, 256, 0, stream>>>(pcm, pcs, v0);
  k_sink_init<<<dim3(128, B_), 256, 0, stream>>>(C, Kp, u0, v0, avec, cp);
  k_bcomb<<<cbGrid, 256, 0, stream>>>(cp, bvec);
  for (int it = 0; it < 28; ++it) {
    k_sink_iterL<<<dim3(128, B_), 256, 0, stream>>>(Kp, bvec, avec, cp);
    k_bcomb<<<cbGrid, 256, 0, stream>>>(cp, bvec);
  }

  // final fused elementwise
  k_felem<<<dim3(N_ / 16, B_), 256, 0, stream>>>(C, Kp, rowm, rowZ, avec, bvec, pc0, sqv, acc);

  k_finalize<<<1, 1, 0, stream>>>(acc, out);
}